// Round 27
// baseline (152.847 us; speedup 1.0000x reference)
//
#include <hip/hip_runtime.h>
#include <hip/hip_bf16.h>
#include <math.h>

// AGTBlock. r25 (130.6us, best) + scan folded into prep via last-block pattern
// (r26's manual attn pipeline regressed; attn reverted to r25 exactly).
//  alpha = Q·K = (Q@Wk^T)·h_src + const(dst) -> Qm = Q@Wk-rows; gather only h.
//  Sum attn·V = (Sum attn·h)@Wv + (Sum attn)·bv -> Wv GEMM fused into final.
//  Fragment-major weights/x; attn V-phase reads LDS-staged rows (u32-typed).
// launches: memset, prep(frags+hist+pos4+scan), mlpqkv+scatter, attn, final.

#define NN 10000
#define NE 320000

typedef __bf16 bf16;
typedef __bf16 bf16x8 __attribute__((ext_vector_type(8)));
typedef __bf16 bf16x4 __attribute__((ext_vector_type(4)));
typedef float f32x4 __attribute__((ext_vector_type(4)));
typedef unsigned char u8;
typedef unsigned int u32;

__device__ __forceinline__ float wave_sum(float v) {
#pragma unroll
  for (int off = 32; off; off >>= 1) v += __shfl_xor(v, off, 64);
  return v;
}

__device__ __forceinline__ float rdlane(float v, int l) {
  return __int_as_float(__builtin_amdgcn_readlane(__float_as_int(v), l));
}

__device__ __forceinline__ int detect64(const int* __restrict__ ei) {
  return (ei[1] | ei[3] | ei[5] | ei[7]) == 0;
}

__device__ __forceinline__ void load_edge(const int* __restrict__ ei, int is64,
                                          int e, int& s, int& dn) {
  if (is64) {
    const long long* e64 = (const long long*)ei;
    s = (int)e64[e];
    dn = (int)e64[NE + e];
  } else {
    s = ei[e];
    dn = ei[NE + e];
  }
  s = min(max(s, 0), NN - 1);
  dn = min(max(dn, 0), NN - 1);
}

// --- prep: frag weights+x, hist, pos4; LAST hist block runs the scan ---
// mats 0,1,2,4,5 transposed (B[n][k]=W[k][n]); mat 3 = Wk NON-transposed.
struct PrepArgs { const float* w[6]; bf16* o[6]; const float* x; bf16* xbf;
                  const int* ei; int* deg; const float* pos; float4* pos4;
                  int* rowptr; int* cursor; };

__global__ __launch_bounds__(256) void prep_kernel(PrepArgs pa) {
  int b = blockIdx.x;
  int w = threadIdx.x >> 6, lane = threadIdx.x & 63;
  int lr = lane & 15, kh = lane >> 4;
  if (b < 192) {  // 6 mats x 128 frags, 1 frag/wave
    int f = b * 4 + w;
    int mat = f >> 7, fr = f & 127;
    int nfp = fr >> 3, kk = fr & 7;
    const float* ws = pa.w[mat];
    bf16x8 o;
    if (mat == 3) {  // Wk rows: contiguous reads
      const float* s = ws + (size_t)(nfp * 16 + lr) * 256 + kk * 32 + kh * 8;
      float4 a0 = *(const float4*)s;
      float4 a1 = *(const float4*)(s + 4);
      o[0] = (bf16)a0.x; o[1] = (bf16)a0.y; o[2] = (bf16)a0.z; o[3] = (bf16)a0.w;
      o[4] = (bf16)a1.x; o[5] = (bf16)a1.y; o[6] = (bf16)a1.z; o[7] = (bf16)a1.w;
    } else {
#pragma unroll
      for (int e = 0; e < 8; ++e)
        o[e] = (bf16)ws[(kk * 32 + kh * 8 + e) * 256 + nfp * 16 + lr];
    }
    *(bf16x8*)(pa.o[mat] + (size_t)fr * 512 + lane * 8) = o;
  } else if (b < 192 + 1250) {  // x -> fragment-major bf16 (5000 frags)
    int g = (b - 192) * 4 + w;
    int rt = g >> 3, kk = g & 7;
    const float* xs = pa.x + (size_t)(rt * 16 + lr) * 256 + kk * 32 + kh * 8;
    float4 a0 = *(const float4*)xs;
    float4 a1 = *(const float4*)(xs + 4);
    bf16x8 o;
    o[0] = (bf16)a0.x; o[1] = (bf16)a0.y; o[2] = (bf16)a0.z; o[3] = (bf16)a0.w;
    o[4] = (bf16)a1.x; o[5] = (bf16)a1.y; o[6] = (bf16)a1.z; o[7] = (bf16)a1.w;
    *(bf16x8*)(pa.xbf + (size_t)g * 512 + lane * 8) = o;
  } else if (b < 192 + 1250 + 1250) {  // histogram + last-block scan
    int is64 = detect64(pa.ei);
    int e = (b - 1442) * 256 + threadIdx.x;
    if (e < NE) {
      int s, dn;
      load_edge(pa.ei, is64, e, s, dn);
      atomicAdd(&pa.deg[dn], 1);
    }
    __shared__ int sdone;
    __syncthreads();
    if (threadIdx.x == 0) {
      __threadfence();
      sdone = atomicAdd(pa.deg + NN, 1);  // counter (memset-zeroed)
    }
    __syncthreads();
    if (sdone == 1249) {  // this block saw all other hist blocks finish
      __shared__ int wsum[4];
      int t = threadIdx.x, wid = t >> 6, ln = t & 63;
      int base = t * 40;  // 256*40 >= NN
      int v[40];
      int s = 0;
#pragma unroll
      for (int i = 0; i < 40; ++i) {
        int idx = base + i;
        v[i] = (idx < NN)
                   ? __hip_atomic_load(&pa.deg[idx], __ATOMIC_RELAXED,
                                       __HIP_MEMORY_SCOPE_AGENT)
                   : 0;
        s += v[i];
      }
      int x = s;
#pragma unroll
      for (int off = 1; off < 64; off <<= 1) {
        int y = __shfl_up(x, off, 64);
        if (ln >= off) x += y;
      }
      if (ln == 63) wsum[wid] = x;
      __syncthreads();
      int waveoff = 0;
      for (int ww = 0; ww < wid; ++ww) waveoff += wsum[ww];
      int run = waveoff + x - s;  // exclusive prefix at this thread's range
#pragma unroll
      for (int i = 0; i < 40; ++i) {
        int idx = base + i;
        if (idx < NN) {
          pa.cursor[idx] = run;
          run += v[i];
          pa.rowptr[idx + 1] = run;
        }
      }
      if (t == 0) pa.rowptr[0] = 0;
    }
  } else {  // pos -> padded float4
    int nn = (b - 2692) * 256 + threadIdx.x;
    if (nn < NN) {
      float4 o;
      o.x = pa.pos[nn * 3];
      o.y = pa.pos[nn * 3 + 1];
      o.z = pa.pos[nn * 3 + 2];
      o.w = 0.0f;
      pa.pos4[nn] = o;
    }
  }
}

// ---- fused node chain x->h1->h->Q->Qm (blocks 0..624) + scatter (625..) ----
#define LP 264

__global__ __launch_bounds__(256) void mlpqkv_kernel(
    const bf16* __restrict__ xbf, const bf16* __restrict__ btf,
    const float* __restrict__ bm1, const float* __restrict__ bm2,
    const float* __restrict__ bq, bf16* __restrict__ hb,
    u8* __restrict__ Hf, u8* __restrict__ Qmf,
    const int* __restrict__ ei, int* __restrict__ cursor,
    int* __restrict__ srcs) {
  __shared__ bf16 lds[16 * LP];
  if (blockIdx.x >= 625) {  // scatter part (block-uniform branch; overlaps)
    int is64 = detect64(ei);
    int e = (blockIdx.x - 625) * 256 + threadIdx.x;
    if (e < NE) {
      int s, dn;
      load_edge(ei, is64, e, s, dn);
      int slot = atomicAdd(&cursor[dn], 1);
      if (slot >= 0 && slot < NE) srcs[slot] = s;
    }
    return;
  }
  int w = threadIdx.x >> 6, lane = threadIdx.x & 63;
  int lr = lane & 15, kh = lane >> 4;
  int rb = blockIdx.x * 16;  // NN = 625*16 exactly
  f32x4 acc[4];
  // stage 1: h1 = relu(x@Wm1+bm1) -> LDS
#pragma unroll
  for (int nf = 0; nf < 4; ++nf) acc[nf] = (f32x4){0, 0, 0, 0};
  {
    const bf16* Af = xbf + (size_t)blockIdx.x * 4096;
#pragma unroll
    for (int kk = 0; kk < 8; ++kk) {
      bf16x8 af = *(const bf16x8*)(Af + kk * 512 + lane * 8);
#pragma unroll
      for (int nf = 0; nf < 4; ++nf) {
        bf16x8 bfr = *(const bf16x8*)(btf + (size_t)(((w * 4 + nf) * 8 + kk) * 512) + lane * 8);
        acc[nf] = __builtin_amdgcn_mfma_f32_16x16x32_bf16(af, bfr, acc[nf], 0, 0, 0);
      }
    }
  }
#pragma unroll
  for (int nf = 0; nf < 4; ++nf) {
    int c = w * 64 + nf * 16 + lr;
    float b1 = bm1[c];
#pragma unroll
    for (int j = 0; j < 4; ++j)
      lds[(kh * 4 + j) * LP + c] = (bf16)fmaxf(acc[nf][j] + b1, 0.0f);
  }
  __syncthreads();
  // stage 2: h = h1(LDS)@Wm2+bm2 -> LDS + hb(bf16) + Hf(fp8 8h)
  bf16x8 haf[8];
#pragma unroll
  for (int kk = 0; kk < 8; ++kk)
    haf[kk] = *(const bf16x8*)(lds + lr * LP + kh * 8 + kk * 32);
#pragma unroll
  for (int nf = 0; nf < 4; ++nf) acc[nf] = (f32x4){0, 0, 0, 0};
  {
    const bf16* Bf = btf + 65536;
#pragma unroll
    for (int kk = 0; kk < 8; ++kk) {
#pragma unroll
      for (int nf = 0; nf < 4; ++nf) {
        bf16x8 bfr = *(const bf16x8*)(Bf + (size_t)(((w * 4 + nf) * 8 + kk) * 512) + lane * 8);
        acc[nf] = __builtin_amdgcn_mfma_f32_16x16x32_bf16(haf[kk], bfr, acc[nf], 0, 0, 0);
      }
    }
  }
  __syncthreads();  // h1 reads complete before overwrite
#pragma unroll
  for (int nf = 0; nf < 4; ++nf) {
    int c = w * 64 + nf * 16 + lr;
    float b2 = bm2[c];
#pragma unroll
    for (int j = 0; j < 4; ++j) {
      int r = rb + kh * 4 + j;
      float v = acc[nf][j] + b2;
      lds[(kh * 4 + j) * LP + c] = (bf16)v;
      hb[(size_t)r * 256 + c] = (bf16)v;
      int pk = __builtin_amdgcn_cvt_pk_fp8_f32(v * 8.0f, v * 8.0f, 0, false);
      Hf[(size_t)r * 256 + c] = (u8)(pk & 0xff);
    }
  }
  __syncthreads();
  // stage 3: Q = h(LDS)@Wq+bq -> LDS
#pragma unroll
  for (int kk = 0; kk < 8; ++kk)
    haf[kk] = *(const bf16x8*)(lds + lr * LP + kh * 8 + kk * 32);
#pragma unroll
  for (int nf = 0; nf < 4; ++nf) acc[nf] = (f32x4){0, 0, 0, 0};
  {
    const bf16* Bf = btf + 2 * 65536;
#pragma unroll
    for (int kk = 0; kk < 8; ++kk) {
#pragma unroll
      for (int nf = 0; nf < 4; ++nf) {
        bf16x8 bfr = *(const bf16x8*)(Bf + (size_t)(((w * 4 + nf) * 8 + kk) * 512) + lane * 8);
        acc[nf] = __builtin_amdgcn_mfma_f32_16x16x32_bf16(haf[kk], bfr, acc[nf], 0, 0, 0);
      }
    }
  }
  __syncthreads();  // h reads complete before overwrite
#pragma unroll
  for (int nf = 0; nf < 4; ++nf) {
    int c = w * 64 + nf * 16 + lr;
    float bx = bq[c];
#pragma unroll
    for (int j = 0; j < 4; ++j)
      lds[(kh * 4 + j) * LP + c] = (bf16)(acc[nf][j] + bx);
  }
  __syncthreads();
  // stage 4: Qm = Q(LDS) @ Wk-rows (no bias; per-dst consts cancel in softmax)
#pragma unroll
  for (int kk = 0; kk < 8; ++kk)
    haf[kk] = *(const bf16x8*)(lds + lr * LP + kh * 8 + kk * 32);
#pragma unroll
  for (int nf = 0; nf < 4; ++nf) acc[nf] = (f32x4){0, 0, 0, 0};
  {
    const bf16* Bf = btf + 3 * 65536;
#pragma unroll
    for (int kk = 0; kk < 8; ++kk) {
#pragma unroll
      for (int nf = 0; nf < 4; ++nf) {
        bf16x8 bfr = *(const bf16x8*)(Bf + (size_t)(((w * 4 + nf) * 8 + kk) * 512) + lane * 8);
        acc[nf] = __builtin_amdgcn_mfma_f32_16x16x32_bf16(haf[kk], bfr, acc[nf], 0, 0, 0);
      }
    }
  }
#pragma unroll
  for (int nf = 0; nf < 4; ++nf) {
    int c = w * 64 + nf * 16 + lr;
#pragma unroll
    for (int j = 0; j < 4; ++j) {
      int r = rb + kh * 4 + j;
      float v = acc[nf][j] * 512.0f;
      int pk = __builtin_amdgcn_cvt_pk_fp8_f32(v, v, 0, false);
      Qmf[(size_t)r * 256 + c] = (u8)(pk & 0xff);
    }
  }
}

// --- attn (r25-proven): single h-gather; LDS-staged rows; pos4 gather ---
#define HPW 66  // staging pitch in words (264B)

__global__ __launch_bounds__(256) void attn_kernel(
    const u8* __restrict__ Qmf, const u8* __restrict__ Hf,
    const float4* __restrict__ pos4, const float* __restrict__ Wp1,
    const float* __restrict__ bp1,
    const int* __restrict__ rowptr, const int* __restrict__ srcs,
    bf16* __restrict__ accH, bf16* __restrict__ acc2, float* __restrict__ sattn) {
  __shared__ u32 hstage[4][16 * HPW];
  int wv = threadIdx.x >> 6;
  int n = blockIdx.x * 4 + wv;
  int lane = threadIdx.x & 63;
  int lr = lane & 15, kh = lane >> 4;
  int d = lane * 4;
  int e0 = min(max(rowptr[n], 0), NE);
  int e1 = min(max(rowptr[n + 1], e0), NE);
  long long qfr[8];
#pragma unroll
  for (int m = 0; m < 8; ++m)
    qfr[m] = *(const long long*)(Qmf + (size_t)n * 256 + m * 32 + kh * 8);
  float4 pn = pos4[n];
  float w0[4], w1[4], w2[4], bp[4];
#pragma unroll
  for (int j = 0; j < 4; ++j) {
    w0[j] = Wp1[d + j];
    w1[j] = Wp1[256 + d + j];
    w2[j] = Wp1[512 + d + j];
    bp[j] = bp1[d + j];
  }
  u32* hs = hstage[wv];
  float aV[4] = {0, 0, 0, 0}, aP[4] = {0, 0, 0, 0};
  float dpart = 0.0f;
  int sv = (e0 < e1) ? srcs[min(e0 + lr, e1 - 1)] : 0;
  for (int base = e0; base < e1; base += 16) {
    int nb = base + 16;
    int svn = (nb < e1) ? srcs[min(nb + lr, e1 - 1)] : 0;  // prefetch next
    // per-lane pos diff of this lane's edge (shared via readlane in V phase)
    float4 ps = pos4[sv];
    float pdx = ps.x - pn.x, pdy = ps.y - pn.y, pdz = ps.z - pn.z;
    long long hfr[8];
#pragma unroll
    for (int m = 0; m < 8; ++m)
      hfr[m] = *(const long long*)(Hf + (size_t)sv * 256 + m * 32 + kh * 8);
    // stage this wave's 16 gathered rows to LDS (u32 stores; same type as read)
#pragma unroll
    for (int m = 0; m < 8; ++m) {
      int wi = lr * HPW + m * 8 + kh * 2;
      hs[wi] = (u32)(unsigned long long)hfr[m];
      hs[wi + 1] = (u32)(((unsigned long long)hfr[m]) >> 32);
    }
    __builtin_amdgcn_sched_barrier(0);  // keep LDS reads below the writes
    f32x4 al = {0.0f, 0.0f, 0.0f, 0.0f};
#pragma unroll
    for (int m = 0; m < 8; ++m)
      al = __builtin_amdgcn_mfma_f32_16x16x32_fp8_fp8(hfr[m], qfr[m], al, 0, 0, 0);
    float wg[4];
#pragma unroll
    for (int j = 0; j < 4; ++j) {
      int e = base + kh * 4 + j;
      // al = (512 Qm)·(8 h) = 4096 alpha; alpha/16 = al/65536
      wg[j] = (e < e1) ? __expf(al[j] * 1.52587890625e-05f) : 0.0f;
      dpart += wg[j];
    }
#pragma unroll
    for (int ii = 0; ii < 4; ++ii) {
      if (base + ii * 4 < e1) {
#pragma unroll
        for (int j = 0; j < 4; ++j) {
          int i = ii * 4 + j;
          float we = rdlane(wg[j], ii * 16);
          float rx = rdlane(pdx, i), ry = rdlane(pdy, i), rz = rdlane(pdz, i);
          u32 vw = hs[i * HPW + lane];
          float vvf[4];
          vvf[0] = __builtin_amdgcn_cvt_f32_fp8(vw, 0);
          vvf[1] = __builtin_amdgcn_cvt_f32_fp8(vw, 1);
          vvf[2] = __builtin_amdgcn_cvt_f32_fp8(vw, 2);
          vvf[3] = __builtin_amdgcn_cvt_f32_fp8(vw, 3);
#pragma unroll
          for (int jj = 0; jj < 4; ++jj) {
            float p1 = fmaf(rx, w0[jj], fmaf(ry, w1[jj], fmaf(rz, w2[jj], bp[jj])));
            p1 = fmaxf(p1, 0.0f);
            aV[jj] = fmaf(we, vvf[jj], aV[jj]);  // accumulates 8*h
            aP[jj] = fmaf(we, p1, aP[jj]);
          }
        }
      }
    }
    __builtin_amdgcn_sched_barrier(0);  // next chunk's writes stay below reads
    sv = svn;
  }
  float denom = wave_sum(dpart) * (1.0f / 16.0f);  // each edge replicated x16
  float r = 1.0f / (denom + 1e-16f);
  if (lane == 0) sattn[n] = denom * r;
  bf16x4 o1, o2;
#pragma unroll
  for (int j = 0; j < 4; ++j) {
    o1[j] = (bf16)(aV[j] * r * 0.125f);  // undo 8x h scale
    o2[j] = (bf16)(aP[j] * r);
  }
  *(bf16x4*)(accH + (size_t)n * 256 + d) = o1;
  *(bf16x4*)(acc2 + (size_t)n * 256 + d) = o2;
}

// ---- final: accH@Wv + acc2@Wp2 (fragment-major B) + residuals + 2x LN ----
__global__ __launch_bounds__(256) void final_kernel(
    const bf16* __restrict__ accH, const bf16* __restrict__ acc2,
    const bf16* __restrict__ BtWv, const bf16* __restrict__ BtWp2,
    const float* __restrict__ sattn, const float* __restrict__ bv,
    const float* __restrict__ bp2, const bf16* __restrict__ hb,
    const float* __restrict__ x, const float* __restrict__ g1,
    const float* __restrict__ b1n, const float* __restrict__ g2,
    const float* __restrict__ b2n, float* __restrict__ out) {
  __shared__ float red[2][4][16];
  int w = threadIdx.x >> 6, lane = threadIdx.x & 63;
  int lr = lane & 15, kh = lane >> 4;
  int rb = blockIdx.x * 16;  // NN = 625*16 exactly
  int arow = rb + lr;
  const bf16* ApH = accH + (size_t)arow * 256 + kh * 8;
  const bf16* ApP = acc2 + (size_t)arow * 256 + kh * 8;
  f32x4 acc[4];
#pragma unroll
  for (int nf = 0; nf < 4; ++nf) acc[nf] = (f32x4){0, 0, 0, 0};
#pragma unroll
  for (int kk = 0; kk < 8; ++kk) {
    bf16x8 afH = *(const bf16x8*)(ApH + kk * 32);
    bf16x8 afP = *(const bf16x8*)(ApP + kk * 32);
#pragma unroll
    for (int nf = 0; nf < 4; ++nf) {
      bf16x8 b1f = *(const bf16x8*)(BtWv + (size_t)(((w * 4 + nf) * 8 + kk) * 512) + lane * 8);
      acc[nf] = __builtin_amdgcn_mfma_f32_16x16x32_bf16(afH, b1f, acc[nf], 0, 0, 0);
      bf16x8 b2f = *(const bf16x8*)(BtWp2 + (size_t)(((w * 4 + nf) * 8 + kk) * 512) + lane * 8);
      acc[nf] = __builtin_amdgcn_mfma_f32_16x16x32_bf16(afP, b2f, acc[nf], 0, 0, 0);
    }
  }
  int rows[4];
  float sr[4];
#pragma unroll
  for (int j = 0; j < 4; ++j) {
    rows[j] = rb + kh * 4 + j;
    sr[j] = sattn[rows[j]];
  }
  // phase A: v = GEMMs + s*(bv+bp2) + h ; mean/var via sum & sumsq
  float s1[4] = {0, 0, 0, 0}, s2[4] = {0, 0, 0, 0};
#pragma unroll
  for (int nf = 0; nf < 4; ++nf) {
    int c = w * 64 + nf * 16 + lr;
    float bb = bv[c] + bp2[c];
#pragma unroll
    for (int j = 0; j < 4; ++j) {
      size_t idx = (size_t)rows[j] * 256 + c;
      float v = acc[nf][j] + sr[j] * bb + (float)hb[idx];
      acc[nf][j] = v;
      s1[j] += v;
      s2[j] += v * v;
    }
  }
#pragma unroll
  for (int j = 0; j < 4; ++j) {
#pragma unroll
    for (int off = 1; off < 16; off <<= 1) {
      s1[j] += __shfl_xor(s1[j], off, 64);
      s2[j] += __shfl_xor(s2[j], off, 64);
    }
  }
  if (lr == 0) {
#pragma unroll
    for (int j = 0; j < 4; ++j) {
      red[0][w][kh * 4 + j] = s1[j];
      red[1][w][kh * 4 + j] = s2[j];
    }
  }
  __syncthreads();
  float mu[4], rstd[4];
#pragma unroll
  for (int j = 0; j < 4; ++j) {
    int r = kh * 4 + j;
    float t1 = red[0][0][r] + red[0][1][r] + red[0][2][r] + red[0][3][r];
    float t2 = red[1][0][r] + red[1][1][r] + red[1][2][r] + red[1][3][r];
    mu[j] = t1 * (1.0f / 256.0f);
    rstd[j] = rsqrtf(t2 * (1.0f / 256.0f) - mu[j] * mu[j] + 1e-5f);
  }
  __syncthreads();
  // phase B: u = LN1*g1 + b1n + x ; second mean/var
#pragma unroll
  for (int j = 0; j < 4; ++j) { s1[j] = 0; s2[j] = 0; }
#pragma unroll
  for (int nf = 0; nf < 4; ++nf) {
    int c = w * 64 + nf * 16 + lr;
#pragma unroll
    for (int j = 0; j < 4; ++j) {
      float u = (acc[nf][j] - mu[j]) * rstd[j] * g1[c] + b1n[c] +
                x[(size_t)rows[j] * 256 + c];
      acc[nf][j] = u;
      s1[j] += u;
      s2[j] += u * u;
    }
  }
#pragma unroll
  for (int j = 0; j < 4; ++j) {
#pragma unroll
    for (int off = 1; off < 16; off <<= 1) {
      s1[j] += __shfl_xor(s1[j], off, 64);
      s2[j] += __shfl_xor(s2[j], off, 64);
    }
  }
  if (lr == 0) {
#pragma unroll
    for (int j = 0; j < 4; ++j) {
      red[0][w][kh * 4 + j] = s1[j];
      red[1][w][kh * 4 + j] = s2[j];
    }
  }
  __syncthreads();
#pragma unroll
  for (int j = 0; j < 4; ++j) {
    int r = kh * 4 + j;
    float t1 = red[0][0][r] + red[0][1][r] + red[0][2][r] + red[0][3][r];
    float t2 = red[1][0][r] + red[1][1][r] + red[1][2][r] + red[1][3][r];
    mu[j] = t1 * (1.0f / 256.0f);
    rstd[j] = rsqrtf(t2 * (1.0f / 256.0f) - mu[j] * mu[j] + 1e-5f);
  }
  // phase C: out = LN2*g2 + b2n
#pragma unroll
  for (int j = 0; j < 4; ++j) {
#pragma unroll
    for (int nf = 0; nf < 4; ++nf) {
      int c = w * 64 + nf * 16 + lr;
      out[(size_t)rows[j] * 256 + c] =
          (acc[nf][j] - mu[j]) * rstd[j] * g2[c] + b2n[c];
    }
  }
}

extern "C" void kernel_launch(void* const* d_in, const int* in_sizes, int n_in,
                              void* d_out, int out_size, void* d_ws, size_t ws_size,
                              hipStream_t stream) {
  (void)in_sizes; (void)n_in; (void)out_size; (void)ws_size;
  const float* x   = (const float*)d_in[0];
  const int*   ei  = (const int*)d_in[1];
  const float* pos = (const float*)d_in[2];
  const float* Wm1 = (const float*)d_in[3];
  const float* bm1 = (const float*)d_in[4];
  const float* Wm2 = (const float*)d_in[5];
  const float* bm2 = (const float*)d_in[6];
  const float* Wq  = (const float*)d_in[7];
  const float* bq  = (const float*)d_in[8];
  const float* Wk  = (const float*)d_in[9];
  const float* bk  = (const float*)d_in[10];
  const float* Wv  = (const float*)d_in[11];
  const float* bv  = (const float*)d_in[12];
  const float* Wp1 = (const float*)d_in[13];
  const float* bp1 = (const float*)d_in[14];
  const float* Wp2 = (const float*)d_in[15];
  const float* bp2 = (const float*)d_in[16];
  const float* g1  = (const float*)d_in[17];
  const float* b1n = (const float*)d_in[18];
  const float* g2  = (const float*)d_in[19];
  const float* b2n = (const float*)d_in[20];
  (void)bk;  // per-dst const Q·bk cancels in segment softmax

  const size_t ND = (size_t)NN * 256;
  char* p = (char*)d_ws;
  auto alloc = [&](size_t bytes) {
    char* r = p;
    p += (bytes + 255) & ~(size_t)255;
    return r;
  };
  bf16* btbase = (bf16*)alloc(6 * 65536 * sizeof(bf16));
  bf16* xbf   = (bf16*)alloc(ND * 2);
  bf16* hb    = (bf16*)alloc(ND * 2);
  u8*   Hf    = (u8*)alloc(ND);
  u8*   Qmf   = (u8*)alloc(ND);
  bf16* accH  = (bf16*)alloc(ND * 2);
  bf16* acc2  = (bf16*)alloc(ND * 2);
  float* sattn = (float*)alloc(NN * 4);
  float4* pos4 = (float4*)alloc(NN * 16);
  int* deg    = (int*)alloc((NN + 1) * 4);  // +1: last-block counter
  int* rowptr = (int*)alloc((NN + 1) * 4);
  int* cursor = (int*)alloc(NN * 4);
  int* srcs   = (int*)alloc(NE * 4);

  hipMemsetAsync(deg, 0, (NN + 1) * 4, stream);

  PrepArgs pa;
  pa.w[0] = Wm1; pa.w[1] = Wm2; pa.w[2] = Wq; pa.w[3] = Wk; pa.w[4] = Wv; pa.w[5] = Wp2;
  for (int i = 0; i < 6; ++i) pa.o[i] = btbase + i * 65536;
  pa.x = x; pa.xbf = xbf; pa.ei = ei; pa.deg = deg;
  pa.pos = pos; pa.pos4 = pos4;
  pa.rowptr = rowptr; pa.cursor = cursor;
  prep_kernel<<<192 + 1250 + 1250 + 40, 256, 0, stream>>>(pa);

  mlpqkv_kernel<<<625 + (NE + 255) / 256, 256, 0, stream>>>(
      xbf, btbase, bm1, bm2, bq, hb, Hf, Qmf, ei, cursor, srcs);

  attn_kernel<<<NN / 4, 256, 0, stream>>>(Qmf, Hf, pos4, Wp1, bp1, rowptr, srcs,
                                          accH, acc2, sattn);

  final_kernel<<<NN / 16, 256, 0, stream>>>(accH, acc2, btbase + 4 * 65536,
                                            btbase + 5 * 65536, sattn, bv, bp2,
                                            hb, x, g1, b1n, g2, b2n,
                                            (float*)d_out);
}

// Round 28
// 130.701 us; speedup vs baseline: 1.1694x; 1.1694x over previous
//
#include <hip/hip_runtime.h>
#include <hip/hip_bf16.h>
#include <math.h>

// AGTBlock. r25 (130.6us, best) + mlpqkv stage-1 x-prefetch (8 A-fragment
// loads issued up front; xbf is HBM-resident unlike L2-hot weights).
// (r26 manual attn pipeline and r27 scan-fold both regressed; reverted.)
//  alpha = Q·K = (Q@Wk^T)·h_src + const(dst) -> Qm = Q@Wk-rows; gather only h.
//  Sum attn·V = (Sum attn·h)@Wv + (Sum attn)·bv -> Wv GEMM fused into final.
//  Fragment-major weights/x; attn V-phase reads LDS-staged rows (u32-typed).
// launches: memset, prep(frags+hist+pos4), scan, mlpqkv+scatter, attn, final.

#define NN 10000
#define NE 320000

typedef __bf16 bf16;
typedef __bf16 bf16x8 __attribute__((ext_vector_type(8)));
typedef __bf16 bf16x4 __attribute__((ext_vector_type(4)));
typedef float f32x4 __attribute__((ext_vector_type(4)));
typedef unsigned char u8;
typedef unsigned int u32;

__device__ __forceinline__ float wave_sum(float v) {
#pragma unroll
  for (int off = 32; off; off >>= 1) v += __shfl_xor(v, off, 64);
  return v;
}

__device__ __forceinline__ float rdlane(float v, int l) {
  return __int_as_float(__builtin_amdgcn_readlane(__float_as_int(v), l));
}

__device__ __forceinline__ int detect64(const int* __restrict__ ei) {
  return (ei[1] | ei[3] | ei[5] | ei[7]) == 0;
}

__device__ __forceinline__ void load_edge(const int* __restrict__ ei, int is64,
                                          int e, int& s, int& dn) {
  if (is64) {
    const long long* e64 = (const long long*)ei;
    s = (int)e64[e];
    dn = (int)e64[NE + e];
  } else {
    s = ei[e];
    dn = ei[NE + e];
  }
  s = min(max(s, 0), NN - 1);
  dn = min(max(dn, 0), NN - 1);
}

// --- prep: weights+x -> fragment-major bf16, + edge histogram + pos4 ---
// mats 0,1,2,4,5 transposed (B[n][k]=W[k][n]); mat 3 = Wk NON-transposed.
struct PrepArgs { const float* w[6]; bf16* o[6]; const float* x; bf16* xbf;
                  const int* ei; int* deg; const float* pos; float4* pos4; };

__global__ __launch_bounds__(256) void prep_kernel(PrepArgs pa) {
  int b = blockIdx.x;
  int w = threadIdx.x >> 6, lane = threadIdx.x & 63;
  int lr = lane & 15, kh = lane >> 4;
  if (b < 192) {  // 6 mats x 128 frags, 1 frag/wave
    int f = b * 4 + w;
    int mat = f >> 7, fr = f & 127;
    int nfp = fr >> 3, kk = fr & 7;
    const float* ws = pa.w[mat];
    bf16x8 o;
    if (mat == 3) {  // Wk rows: contiguous reads
      const float* s = ws + (size_t)(nfp * 16 + lr) * 256 + kk * 32 + kh * 8;
      float4 a0 = *(const float4*)s;
      float4 a1 = *(const float4*)(s + 4);
      o[0] = (bf16)a0.x; o[1] = (bf16)a0.y; o[2] = (bf16)a0.z; o[3] = (bf16)a0.w;
      o[4] = (bf16)a1.x; o[5] = (bf16)a1.y; o[6] = (bf16)a1.z; o[7] = (bf16)a1.w;
    } else {
#pragma unroll
      for (int e = 0; e < 8; ++e)
        o[e] = (bf16)ws[(kk * 32 + kh * 8 + e) * 256 + nfp * 16 + lr];
    }
    *(bf16x8*)(pa.o[mat] + (size_t)fr * 512 + lane * 8) = o;
  } else if (b < 192 + 1250) {  // x -> fragment-major bf16 (5000 frags)
    int g = (b - 192) * 4 + w;
    int rt = g >> 3, kk = g & 7;
    const float* xs = pa.x + (size_t)(rt * 16 + lr) * 256 + kk * 32 + kh * 8;
    float4 a0 = *(const float4*)xs;
    float4 a1 = *(const float4*)(xs + 4);
    bf16x8 o;
    o[0] = (bf16)a0.x; o[1] = (bf16)a0.y; o[2] = (bf16)a0.z; o[3] = (bf16)a0.w;
    o[4] = (bf16)a1.x; o[5] = (bf16)a1.y; o[6] = (bf16)a1.z; o[7] = (bf16)a1.w;
    *(bf16x8*)(pa.xbf + (size_t)g * 512 + lane * 8) = o;
  } else if (b < 192 + 1250 + 1250) {  // histogram of dst (deg pre-zeroed)
    int is64 = detect64(pa.ei);
    int e = (b - 1442) * 256 + threadIdx.x;
    if (e < NE) {
      int s, dn;
      load_edge(pa.ei, is64, e, s, dn);
      atomicAdd(&pa.deg[dn], 1);
    }
  } else {  // pos -> padded float4
    int nn = (b - 2692) * 256 + threadIdx.x;
    if (nn < NN) {
      float4 o;
      o.x = pa.pos[nn * 3];
      o.y = pa.pos[nn * 3 + 1];
      o.z = pa.pos[nn * 3 + 2];
      o.w = 0.0f;
      pa.pos4[nn] = o;
    }
  }
}

__global__ __launch_bounds__(1024) void scan_kernel(
    const int* __restrict__ deg, int* __restrict__ rowptr,
    int* __restrict__ cursor) {
  __shared__ int wsum[16];
  int t = threadIdx.x, wid = t >> 6, lane = t & 63;
  int base = t * 10;
  int v[10];
  int s = 0;
#pragma unroll
  for (int i = 0; i < 10; ++i) {
    int idx = base + i;
    v[i] = (idx < NN) ? deg[idx] : 0;
    s += v[i];
  }
  int x = s;
#pragma unroll
  for (int off = 1; off < 64; off <<= 1) {
    int y = __shfl_up(x, off, 64);
    if (lane >= off) x += y;
  }
  if (lane == 63) wsum[wid] = x;
  __syncthreads();
  if (wid == 0) {
    int ws = (lane < 16) ? wsum[lane] : 0;
#pragma unroll
    for (int off = 1; off < 16; off <<= 1) {
      int y = __shfl_up(ws, off, 64);
      if (lane >= off) ws += y;
    }
    if (lane < 16) wsum[lane] = ws;
  }
  __syncthreads();
  int run = ((wid > 0) ? wsum[wid - 1] : 0) + x - s;  // exclusive prefix
#pragma unroll
  for (int i = 0; i < 10; ++i) {
    int idx = base + i;
    if (idx < NN) {
      cursor[idx] = run;
      run += v[i];
      rowptr[idx + 1] = run;
    }
  }
  if (t == 0) rowptr[0] = 0;
}

// ---- fused node chain x->h1->h->Q->Qm (blocks 0..624) + scatter (625..) ----
#define LP 264

__global__ __launch_bounds__(256) void mlpqkv_kernel(
    const bf16* __restrict__ xbf, const bf16* __restrict__ btf,
    const float* __restrict__ bm1, const float* __restrict__ bm2,
    const float* __restrict__ bq, bf16* __restrict__ hb,
    u8* __restrict__ Hf, u8* __restrict__ Qmf,
    const int* __restrict__ ei, int* __restrict__ cursor,
    int* __restrict__ srcs) {
  __shared__ bf16 lds[16 * LP];
  if (blockIdx.x >= 625) {  // scatter part (block-uniform branch; overlaps)
    int is64 = detect64(ei);
    int e = (blockIdx.x - 625) * 256 + threadIdx.x;
    if (e < NE) {
      int s, dn;
      load_edge(ei, is64, e, s, dn);
      int slot = atomicAdd(&cursor[dn], 1);
      if (slot >= 0 && slot < NE) srcs[slot] = s;
    }
    return;
  }
  int w = threadIdx.x >> 6, lane = threadIdx.x & 63;
  int lr = lane & 15, kh = lane >> 4;
  int rb = blockIdx.x * 16;  // NN = 625*16 exactly
  f32x4 acc[4];
  // stage 1: h1 = relu(x@Wm1+bm1) -> LDS; all 8 HBM A-fragments prefetched
#pragma unroll
  for (int nf = 0; nf < 4; ++nf) acc[nf] = (f32x4){0, 0, 0, 0};
  {
    const bf16* Af = xbf + (size_t)blockIdx.x * 4096;
    bf16x8 af[8];
#pragma unroll
    for (int kk = 0; kk < 8; ++kk)
      af[kk] = *(const bf16x8*)(Af + kk * 512 + lane * 8);
#pragma unroll
    for (int kk = 0; kk < 8; ++kk) {
#pragma unroll
      for (int nf = 0; nf < 4; ++nf) {
        bf16x8 bfr = *(const bf16x8*)(btf + (size_t)(((w * 4 + nf) * 8 + kk) * 512) + lane * 8);
        acc[nf] = __builtin_amdgcn_mfma_f32_16x16x32_bf16(af[kk], bfr, acc[nf], 0, 0, 0);
      }
    }
  }
#pragma unroll
  for (int nf = 0; nf < 4; ++nf) {
    int c = w * 64 + nf * 16 + lr;
    float b1 = bm1[c];
#pragma unroll
    for (int j = 0; j < 4; ++j)
      lds[(kh * 4 + j) * LP + c] = (bf16)fmaxf(acc[nf][j] + b1, 0.0f);
  }
  __syncthreads();
  // stage 2: h = h1(LDS)@Wm2+bm2 -> LDS + hb(bf16) + Hf(fp8 8h)
  bf16x8 haf[8];
#pragma unroll
  for (int kk = 0; kk < 8; ++kk)
    haf[kk] = *(const bf16x8*)(lds + lr * LP + kh * 8 + kk * 32);
#pragma unroll
  for (int nf = 0; nf < 4; ++nf) acc[nf] = (f32x4){0, 0, 0, 0};
  {
    const bf16* Bf = btf + 65536;
#pragma unroll
    for (int kk = 0; kk < 8; ++kk) {
#pragma unroll
      for (int nf = 0; nf < 4; ++nf) {
        bf16x8 bfr = *(const bf16x8*)(Bf + (size_t)(((w * 4 + nf) * 8 + kk) * 512) + lane * 8);
        acc[nf] = __builtin_amdgcn_mfma_f32_16x16x32_bf16(haf[kk], bfr, acc[nf], 0, 0, 0);
      }
    }
  }
  __syncthreads();  // h1 reads complete before overwrite
#pragma unroll
  for (int nf = 0; nf < 4; ++nf) {
    int c = w * 64 + nf * 16 + lr;
    float b2 = bm2[c];
#pragma unroll
    for (int j = 0; j < 4; ++j) {
      int r = rb + kh * 4 + j;
      float v = acc[nf][j] + b2;
      lds[(kh * 4 + j) * LP + c] = (bf16)v;
      hb[(size_t)r * 256 + c] = (bf16)v;
      int pk = __builtin_amdgcn_cvt_pk_fp8_f32(v * 8.0f, v * 8.0f, 0, false);
      Hf[(size_t)r * 256 + c] = (u8)(pk & 0xff);
    }
  }
  __syncthreads();
  // stage 3: Q = h(LDS)@Wq+bq -> LDS
#pragma unroll
  for (int kk = 0; kk < 8; ++kk)
    haf[kk] = *(const bf16x8*)(lds + lr * LP + kh * 8 + kk * 32);
#pragma unroll
  for (int nf = 0; nf < 4; ++nf) acc[nf] = (f32x4){0, 0, 0, 0};
  {
    const bf16* Bf = btf + 2 * 65536;
#pragma unroll
    for (int kk = 0; kk < 8; ++kk) {
#pragma unroll
      for (int nf = 0; nf < 4; ++nf) {
        bf16x8 bfr = *(const bf16x8*)(Bf + (size_t)(((w * 4 + nf) * 8 + kk) * 512) + lane * 8);
        acc[nf] = __builtin_amdgcn_mfma_f32_16x16x32_bf16(haf[kk], bfr, acc[nf], 0, 0, 0);
      }
    }
  }
  __syncthreads();  // h reads complete before overwrite
#pragma unroll
  for (int nf = 0; nf < 4; ++nf) {
    int c = w * 64 + nf * 16 + lr;
    float bx = bq[c];
#pragma unroll
    for (int j = 0; j < 4; ++j)
      lds[(kh * 4 + j) * LP + c] = (bf16)(acc[nf][j] + bx);
  }
  __syncthreads();
  // stage 4: Qm = Q(LDS) @ Wk-rows (no bias; per-dst consts cancel in softmax)
#pragma unroll
  for (int kk = 0; kk < 8; ++kk)
    haf[kk] = *(const bf16x8*)(lds + lr * LP + kh * 8 + kk * 32);
#pragma unroll
  for (int nf = 0; nf < 4; ++nf) acc[nf] = (f32x4){0, 0, 0, 0};
  {
    const bf16* Bf = btf + 3 * 65536;
#pragma unroll
    for (int kk = 0; kk < 8; ++kk) {
#pragma unroll
      for (int nf = 0; nf < 4; ++nf) {
        bf16x8 bfr = *(const bf16x8*)(Bf + (size_t)(((w * 4 + nf) * 8 + kk) * 512) + lane * 8);
        acc[nf] = __builtin_amdgcn_mfma_f32_16x16x32_bf16(haf[kk], bfr, acc[nf], 0, 0, 0);
      }
    }
  }
#pragma unroll
  for (int nf = 0; nf < 4; ++nf) {
    int c = w * 64 + nf * 16 + lr;
#pragma unroll
    for (int j = 0; j < 4; ++j) {
      int r = rb + kh * 4 + j;
      float v = acc[nf][j] * 512.0f;
      int pk = __builtin_amdgcn_cvt_pk_fp8_f32(v, v, 0, false);
      Qmf[(size_t)r * 256 + c] = (u8)(pk & 0xff);
    }
  }
}

// --- attn (r25-proven): single h-gather; LDS-staged rows; pos4 gather ---
#define HPW 66  // staging pitch in words (264B)

__global__ __launch_bounds__(256) void attn_kernel(
    const u8* __restrict__ Qmf, const u8* __restrict__ Hf,
    const float4* __restrict__ pos4, const float* __restrict__ Wp1,
    const float* __restrict__ bp1,
    const int* __restrict__ rowptr, const int* __restrict__ srcs,
    bf16* __restrict__ accH, bf16* __restrict__ acc2, float* __restrict__ sattn) {
  __shared__ u32 hstage[4][16 * HPW];
  int wv = threadIdx.x >> 6;
  int n = blockIdx.x * 4 + wv;
  int lane = threadIdx.x & 63;
  int lr = lane & 15, kh = lane >> 4;
  int d = lane * 4;
  int e0 = min(max(rowptr[n], 0), NE);
  int e1 = min(max(rowptr[n + 1], e0), NE);
  long long qfr[8];
#pragma unroll
  for (int m = 0; m < 8; ++m)
    qfr[m] = *(const long long*)(Qmf + (size_t)n * 256 + m * 32 + kh * 8);
  float4 pn = pos4[n];
  float w0[4], w1[4], w2[4], bp[4];
#pragma unroll
  for (int j = 0; j < 4; ++j) {
    w0[j] = Wp1[d + j];
    w1[j] = Wp1[256 + d + j];
    w2[j] = Wp1[512 + d + j];
    bp[j] = bp1[d + j];
  }
  u32* hs = hstage[wv];
  float aV[4] = {0, 0, 0, 0}, aP[4] = {0, 0, 0, 0};
  float dpart = 0.0f;
  int sv = (e0 < e1) ? srcs[min(e0 + lr, e1 - 1)] : 0;
  for (int base = e0; base < e1; base += 16) {
    int nb = base + 16;
    int svn = (nb < e1) ? srcs[min(nb + lr, e1 - 1)] : 0;  // prefetch next
    // per-lane pos diff of this lane's edge (shared via readlane in V phase)
    float4 ps = pos4[sv];
    float pdx = ps.x - pn.x, pdy = ps.y - pn.y, pdz = ps.z - pn.z;
    long long hfr[8];
#pragma unroll
    for (int m = 0; m < 8; ++m)
      hfr[m] = *(const long long*)(Hf + (size_t)sv * 256 + m * 32 + kh * 8);
    // stage this wave's 16 gathered rows to LDS (u32 stores; same type as read)
#pragma unroll
    for (int m = 0; m < 8; ++m) {
      int wi = lr * HPW + m * 8 + kh * 2;
      hs[wi] = (u32)(unsigned long long)hfr[m];
      hs[wi + 1] = (u32)(((unsigned long long)hfr[m]) >> 32);
    }
    __builtin_amdgcn_sched_barrier(0);  // keep LDS reads below the writes
    f32x4 al = {0.0f, 0.0f, 0.0f, 0.0f};
#pragma unroll
    for (int m = 0; m < 8; ++m)
      al = __builtin_amdgcn_mfma_f32_16x16x32_fp8_fp8(hfr[m], qfr[m], al, 0, 0, 0);
    float wg[4];
#pragma unroll
    for (int j = 0; j < 4; ++j) {
      int e = base + kh * 4 + j;
      // al = (512 Qm)·(8 h) = 4096 alpha; alpha/16 = al/65536
      wg[j] = (e < e1) ? __expf(al[j] * 1.52587890625e-05f) : 0.0f;
      dpart += wg[j];
    }
#pragma unroll
    for (int ii = 0; ii < 4; ++ii) {
      if (base + ii * 4 < e1) {
#pragma unroll
        for (int j = 0; j < 4; ++j) {
          int i = ii * 4 + j;
          float we = rdlane(wg[j], ii * 16);
          float rx = rdlane(pdx, i), ry = rdlane(pdy, i), rz = rdlane(pdz, i);
          u32 vw = hs[i * HPW + lane];
          float vvf[4];
          vvf[0] = __builtin_amdgcn_cvt_f32_fp8(vw, 0);
          vvf[1] = __builtin_amdgcn_cvt_f32_fp8(vw, 1);
          vvf[2] = __builtin_amdgcn_cvt_f32_fp8(vw, 2);
          vvf[3] = __builtin_amdgcn_cvt_f32_fp8(vw, 3);
#pragma unroll
          for (int jj = 0; jj < 4; ++jj) {
            float p1 = fmaf(rx, w0[jj], fmaf(ry, w1[jj], fmaf(rz, w2[jj], bp[jj])));
            p1 = fmaxf(p1, 0.0f);
            aV[jj] = fmaf(we, vvf[jj], aV[jj]);  // accumulates 8*h
            aP[jj] = fmaf(we, p1, aP[jj]);
          }
        }
      }
    }
    __builtin_amdgcn_sched_barrier(0);  // next chunk's writes stay below reads
    sv = svn;
  }
  float denom = wave_sum(dpart) * (1.0f / 16.0f);  // each edge replicated x16
  float r = 1.0f / (denom + 1e-16f);
  if (lane == 0) sattn[n] = denom * r;
  bf16x4 o1, o2;
#pragma unroll
  for (int j = 0; j < 4; ++j) {
    o1[j] = (bf16)(aV[j] * r * 0.125f);  // undo 8x h scale
    o2[j] = (bf16)(aP[j] * r);
  }
  *(bf16x4*)(accH + (size_t)n * 256 + d) = o1;
  *(bf16x4*)(acc2 + (size_t)n * 256 + d) = o2;
}

// ---- final: accH@Wv + acc2@Wp2 (fragment-major B) + residuals + 2x LN ----
__global__ __launch_bounds__(256) void final_kernel(
    const bf16* __restrict__ accH, const bf16* __restrict__ acc2,
    const bf16* __restrict__ BtWv, const bf16* __restrict__ BtWp2,
    const float* __restrict__ sattn, const float* __restrict__ bv,
    const float* __restrict__ bp2, const bf16* __restrict__ hb,
    const float* __restrict__ x, const float* __restrict__ g1,
    const float* __restrict__ b1n, const float* __restrict__ g2,
    const float* __restrict__ b2n, float* __restrict__ out) {
  __shared__ float red[2][4][16];
  int w = threadIdx.x >> 6, lane = threadIdx.x & 63;
  int lr = lane & 15, kh = lane >> 4;
  int rb = blockIdx.x * 16;  // NN = 625*16 exactly
  int arow = rb + lr;
  const bf16* ApH = accH + (size_t)arow * 256 + kh * 8;
  const bf16* ApP = acc2 + (size_t)arow * 256 + kh * 8;
  f32x4 acc[4];
#pragma unroll
  for (int nf = 0; nf < 4; ++nf) acc[nf] = (f32x4){0, 0, 0, 0};
#pragma unroll
  for (int kk = 0; kk < 8; ++kk) {
    bf16x8 afH = *(const bf16x8*)(ApH + kk * 32);
    bf16x8 afP = *(const bf16x8*)(ApP + kk * 32);
#pragma unroll
    for (int nf = 0; nf < 4; ++nf) {
      bf16x8 b1f = *(const bf16x8*)(BtWv + (size_t)(((w * 4 + nf) * 8 + kk) * 512) + lane * 8);
      acc[nf] = __builtin_amdgcn_mfma_f32_16x16x32_bf16(afH, b1f, acc[nf], 0, 0, 0);
      bf16x8 b2f = *(const bf16x8*)(BtWp2 + (size_t)(((w * 4 + nf) * 8 + kk) * 512) + lane * 8);
      acc[nf] = __builtin_amdgcn_mfma_f32_16x16x32_bf16(afP, b2f, acc[nf], 0, 0, 0);
    }
  }
  int rows[4];
  float sr[4];
#pragma unroll
  for (int j = 0; j < 4; ++j) {
    rows[j] = rb + kh * 4 + j;
    sr[j] = sattn[rows[j]];
  }
  // phase A: v = GEMMs + s*(bv+bp2) + h ; mean/var via sum & sumsq
  float s1[4] = {0, 0, 0, 0}, s2[4] = {0, 0, 0, 0};
#pragma unroll
  for (int nf = 0; nf < 4; ++nf) {
    int c = w * 64 + nf * 16 + lr;
    float bb = bv[c] + bp2[c];
#pragma unroll
    for (int j = 0; j < 4; ++j) {
      size_t idx = (size_t)rows[j] * 256 + c;
      float v = acc[nf][j] + sr[j] * bb + (float)hb[idx];
      acc[nf][j] = v;
      s1[j] += v;
      s2[j] += v * v;
    }
  }
#pragma unroll
  for (int j = 0; j < 4; ++j) {
#pragma unroll
    for (int off = 1; off < 16; off <<= 1) {
      s1[j] += __shfl_xor(s1[j], off, 64);
      s2[j] += __shfl_xor(s2[j], off, 64);
    }
  }
  if (lr == 0) {
#pragma unroll
    for (int j = 0; j < 4; ++j) {
      red[0][w][kh * 4 + j] = s1[j];
      red[1][w][kh * 4 + j] = s2[j];
    }
  }
  __syncthreads();
  float mu[4], rstd[4];
#pragma unroll
  for (int j = 0; j < 4; ++j) {
    int r = kh * 4 + j;
    float t1 = red[0][0][r] + red[0][1][r] + red[0][2][r] + red[0][3][r];
    float t2 = red[1][0][r] + red[1][1][r] + red[1][2][r] + red[1][3][r];
    mu[j] = t1 * (1.0f / 256.0f);
    rstd[j] = rsqrtf(t2 * (1.0f / 256.0f) - mu[j] * mu[j] + 1e-5f);
  }
  __syncthreads();
  // phase B: u = LN1*g1 + b1n + x ; second mean/var
#pragma unroll
  for (int j = 0; j < 4; ++j) { s1[j] = 0; s2[j] = 0; }
#pragma unroll
  for (int nf = 0; nf < 4; ++nf) {
    int c = w * 64 + nf * 16 + lr;
#pragma unroll
    for (int j = 0; j < 4; ++j) {
      float u = (acc[nf][j] - mu[j]) * rstd[j] * g1[c] + b1n[c] +
                x[(size_t)rows[j] * 256 + c];
      acc[nf][j] = u;
      s1[j] += u;
      s2[j] += u * u;
    }
  }
#pragma unroll
  for (int j = 0; j < 4; ++j) {
#pragma unroll
    for (int off = 1; off < 16; off <<= 1) {
      s1[j] += __shfl_xor(s1[j], off, 64);
      s2[j] += __shfl_xor(s2[j], off, 64);
    }
  }
  if (lr == 0) {
#pragma unroll
    for (int j = 0; j < 4; ++j) {
      red[0][w][kh * 4 + j] = s1[j];
      red[1][w][kh * 4 + j] = s2[j];
    }
  }
  __syncthreads();
#pragma unroll
  for (int j = 0; j < 4; ++j) {
    int r = kh * 4 + j;
    float t1 = red[0][0][r] + red[0][1][r] + red[0][2][r] + red[0][3][r];
    float t2 = red[1][0][r] + red[1][1][r] + red[1][2][r] + red[1][3][r];
    mu[j] = t1 * (1.0f / 256.0f);
    rstd[j] = rsqrtf(t2 * (1.0f / 256.0f) - mu[j] * mu[j] + 1e-5f);
  }
  // phase C: out = LN2*g2 + b2n
#pragma unroll
  for (int j = 0; j < 4; ++j) {
#pragma unroll
    for (int nf = 0; nf < 4; ++nf) {
      int c = w * 64 + nf * 16 + lr;
      out[(size_t)rows[j] * 256 + c] =
          (acc[nf][j] - mu[j]) * rstd[j] * g2[c] + b2n[c];
    }
  }
}

extern "C" void kernel_launch(void* const* d_in, const int* in_sizes, int n_in,
                              void* d_out, int out_size, void* d_ws, size_t ws_size,
                              hipStream_t stream) {
  (void)in_sizes; (void)n_in; (void)out_size; (void)ws_size;
  const float* x   = (const float*)d_in[0];
  const int*   ei  = (const int*)d_in[1];
  const float* pos = (const float*)d_in[2];
  const float* Wm1 = (const float*)d_in[3];
  const float* bm1 = (const float*)d_in[4];
  const float* Wm2 = (const float*)d_in[5];
  const float* bm2 = (const float*)d_in[6];
  const float* Wq  = (const float*)d_in[7];
  const float* bq  = (const float*)d_in[8];
  const float* Wk  = (const float*)d_in[9];
  const float* bk  = (const float*)d_in[10];
  const float* Wv  = (const float*)d_in[11];
  const float* bv  = (const float*)d_in[12];
  const float* Wp1 = (const float*)d_in[13];
  const float* bp1 = (const float*)d_in[14];
  const float* Wp2 = (const float*)d_in[15];
  const float* bp2 = (const float*)d_in[16];
  const float* g1  = (const float*)d_in[17];
  const float* b1n = (const float*)d_in[18];
  const float* g2  = (const float*)d_in[19];
  const float* b2n = (const float*)d_in[20];
  (void)bk;  // per-dst const Q·bk cancels in segment softmax

  const size_t ND = (size_t)NN * 256;
  char* p = (char*)d_ws;
  auto alloc = [&](size_t bytes) {
    char* r = p;
    p += (bytes + 255) & ~(size_t)255;
    return r;
  };
  bf16* btbase = (bf16*)alloc(6 * 65536 * sizeof(bf16));
  bf16* xbf   = (bf16*)alloc(ND * 2);
  bf16* hb    = (bf16*)alloc(ND * 2);
  u8*   Hf    = (u8*)alloc(ND);
  u8*   Qmf   = (u8*)alloc(ND);
  bf16* accH  = (bf16*)alloc(ND * 2);
  bf16* acc2  = (bf16*)alloc(ND * 2);
  float* sattn = (float*)alloc(NN * 4);
  float4* pos4 = (float4*)alloc(NN * 16);
  int* deg    = (int*)alloc(NN * 4);
  int* rowptr = (int*)alloc((NN + 1) * 4);
  int* cursor = (int*)alloc(NN * 4);
  int* srcs   = (int*)alloc(NE * 4);

  hipMemsetAsync(deg, 0, NN * 4, stream);

  PrepArgs pa;
  pa.w[0] = Wm1; pa.w[1] = Wm2; pa.w[2] = Wq; pa.w[3] = Wk; pa.w[4] = Wv; pa.w[5] = Wp2;
  for (int i = 0; i < 6; ++i) pa.o[i] = btbase + i * 65536;
  pa.x = x; pa.xbf = xbf; pa.ei = ei; pa.deg = deg;
  pa.pos = pos; pa.pos4 = pos4;
  prep_kernel<<<192 + 1250 + 1250 + 40, 256, 0, stream>>>(pa);

  scan_kernel<<<1, 1024, 0, stream>>>(deg, rowptr, cursor);

  mlpqkv_kernel<<<625 + (NE + 255) / 256, 256, 0, stream>>>(
      xbf, btbase, bm1, bm2, bq, hb, Hf, Qmf, ei, cursor, srcs);

  attn_kernel<<<NN / 4, 256, 0, stream>>>(Qmf, Hf, pos4, Wp1, bp1, rowptr, srcs,
                                          accH, acc2, sattn);

  final_kernel<<<NN / 16, 256, 0, stream>>>(accH, acc2, btbase + 4 * 65536,
                                            btbase + 5 * 65536, sattn, bv, bp2,
                                            hb, x, g1, b1n, g2, b2n,
                                            (float*)d_out);
}